// Round 4
// baseline (1150.638 us; speedup 1.0000x reference)
//
#include <hip/hip_runtime.h>
#include <cstdio>

// ---------------------------------------------------------------------------
// MyGCN: 3-layer GraphConv GCN on MI355X.
// Round 4: attack k_agg's L2-miss traffic (time == (FETCH+WRITE)/3TB/s):
//  - feature-split aggregation: 2 sequential 64-feature passes (gridDim.y is
//    the slow dispatch axis) -> gather working set 25.6->12.8MB, better L2 hit
//  - all N x 128 inter-stage tensors in bf16 (X, M, y) -> halved streams
//  - GraphNorm stats for M fused into k_agg (register values -> shfl -> LDS ->
//    8-way striped global atomics); 3 k_reduce dispatches eliminated
// CSR build: bucketed two-pass (round-2). GEMMs: bf16 MFMA 16x16x32 with
// GraphNorm folded to per-feature affine applied during LDS staging.
// ---------------------------------------------------------------------------

#define HID 128

typedef __attribute__((ext_vector_type(8))) short short8;
typedef __attribute__((ext_vector_type(4))) float floatx4;

__device__ __forceinline__ unsigned short f2bf(float f) {
    unsigned u = __float_as_uint(f);
    unsigned r = (u + 0x7FFFu + ((u >> 16) & 1u)) >> 16;  // RNE
    return (unsigned short)r;
}
__device__ __forceinline__ float bflo(unsigned u) { return __uint_as_float(u << 16); }
__device__ __forceinline__ float bfhi(unsigned u) { return __uint_as_float(u & 0xFFFF0000u); }

// ---------------- bucketed CSR build ----------------
#define NB 512
#define RPB 196
#define CAPB 8192
#define TILE_A 2048

__global__ __launch_bounds__(256) void k_binA(
    const int* __restrict__ row, const int* __restrict__ col,
    const float* __restrict__ ew, int2* __restrict__ binned,
    unsigned* __restrict__ cursor, int E) {
    __shared__ int2 stag[TILE_A];
    __shared__ unsigned short bof[TILE_A];
    __shared__ unsigned hist[NB], scanned[NB], bump[NB];
    __shared__ int delta[NB];
    __shared__ unsigned scanw[256];
    int t = threadIdx.x;
    int tileBase = blockIdx.x * TILE_A;
    int tcnt = min(TILE_A, E - tileBase);

    hist[t] = 0; hist[t + 256] = 0;
    __syncthreads();

    int myb[8]; int2 myv[8];
#pragma unroll
    for (int i = 0; i < 8; ++i) {
        int idx = t + i * 256;
        if (idx < tcnt) {
            int e = tileBase + idx;
            int r = row[e];
            int c = col[e];
            float w = ew[e];
            int b = r / RPB;
            int rl = r - b * RPB;
            myb[i] = b;
            myv[i] = make_int2((rl << 17) | c, __float_as_int(w));
            atomicAdd(&hist[b], 1u);
        } else {
            myb[i] = -1;
            myv[i] = make_int2(0, 0);
        }
    }
    __syncthreads();

    unsigned h0 = hist[2 * t], h1 = hist[2 * t + 1];
    unsigned p = h0 + h1;
    scanw[t] = p;
    __syncthreads();
    for (int o = 1; o < 256; o <<= 1) {
        unsigned x = (t >= o) ? scanw[t - o] : 0u;
        __syncthreads();
        scanw[t] += x;
        __syncthreads();
    }
    unsigned excl = scanw[t] - p;
    scanned[2 * t] = excl;          bump[2 * t] = excl;
    scanned[2 * t + 1] = excl + h0; bump[2 * t + 1] = excl + h0;
    __syncthreads();

#pragma unroll
    for (int j = 0; j < 2; ++j) {
        int b = t + j * 256;
        unsigned c = hist[b];
        if (c) {
            unsigned old = atomicAdd(&cursor[b], c);
            delta[b] = (int)((unsigned)b * CAPB + old) - (int)scanned[b];
        }
    }
    __syncthreads();

#pragma unroll
    for (int i = 0; i < 8; ++i) {
        if (myb[i] >= 0) {
            unsigned s = atomicAdd(&bump[myb[i]], 1u);
            stag[s] = myv[i];
            bof[s] = (unsigned short)myb[i];
        }
    }
    __syncthreads();

    for (int i = t; i < tcnt; i += 256) {
        int b = bof[i];
        int dst = delta[b] + i;
        if (dst < (b + 1) * CAPB) binned[dst] = stag[i];
    }
}

__global__ void k_bscan(const unsigned* __restrict__ cursor, unsigned* __restrict__ outbase) {
    __shared__ unsigned scanw[256];
    int t = threadIdx.x;
    unsigned h0 = min(cursor[2 * t], (unsigned)CAPB);
    unsigned h1 = min(cursor[2 * t + 1], (unsigned)CAPB);
    unsigned p = h0 + h1;
    scanw[t] = p;
    __syncthreads();
    for (int o = 1; o < 256; o <<= 1) {
        unsigned x = (t >= o) ? scanw[t - o] : 0u;
        __syncthreads();
        scanw[t] += x;
        __syncthreads();
    }
    unsigned excl = scanw[t] - p;
    outbase[2 * t] = excl;
    outbase[2 * t + 1] = excl + h0;
}

__global__ __launch_bounds__(256) void k_binB(
    const int2* __restrict__ binned, const unsigned* __restrict__ cursor,
    const unsigned* __restrict__ outbase, int2* __restrict__ edge_s,
    unsigned* __restrict__ endp, unsigned* __restrict__ cntg, int N) {
    __shared__ unsigned hist[256], bump[256], scanw[256];
    __shared__ float wsum[256], inv[256];
    int b = blockIdx.x, t = threadIdx.x;
    size_t base_in = (size_t)b * CAPB;
    unsigned cntb = min(cursor[b], (unsigned)CAPB);
    unsigned outb = outbase[b];

    hist[t] = 0;
    wsum[t] = 0.f;
    __syncthreads();
    for (unsigned i = t; i < cntb; i += 256) {
        int2 v = binned[base_in + i];
        unsigned rl = ((unsigned)v.x) >> 17;
        atomicAdd(&hist[rl], 1u);
        atomicAdd(&wsum[rl], __int_as_float(v.y));
    }
    __syncthreads();

    unsigned h = hist[t];
    scanw[t] = h;
    __syncthreads();
    for (int o = 1; o < 256; o <<= 1) {
        unsigned x = (t >= o) ? scanw[t - o] : 0u;
        __syncthreads();
        scanw[t] += x;
        __syncthreads();
    }
    unsigned excl = scanw[t] - h;
    bump[t] = excl;
    float d = wsum[t];
    d = (d < 0.5f) ? d + 1.0f : d;
    inv[t] = 1.0f / d;
    int grow = b * RPB + t;
    if (t < RPB && grow < N) {
        endp[grow] = outb + excl + h;
        cntg[grow] = h;
    }
    __syncthreads();

    for (unsigned i = t; i < cntb; i += 256) {
        int2 v = binned[base_in + i];
        unsigned rl = ((unsigned)v.x) >> 17;
        unsigned pos = outb + atomicAdd(&bump[rl], 1u);
        float w = __int_as_float(v.y) * inv[rl];
        edge_s[pos] = make_int2(v.x & 0x1FFFF, __float_as_int(w));
    }
}

// ---------------- embedding gather -> bf16 X ----------------
__global__ void k_gather(const int* __restrict__ x_idx, const float* __restrict__ emb,
                         unsigned short* __restrict__ X, int N) {
    int tid = blockIdx.x * blockDim.x + threadIdx.x;  // over N*16 groups of 8 feats
    if (tid < N * 16) {
        int n = tid >> 4, g = tid & 15;
        const float4* e4 = (const float4*)emb;
        size_t base = (size_t)x_idx[n] * 32 + g * 2;
        float4 v0 = e4[base];
        float4 v1 = e4[base + 1];
        uint4 u;
        u.x = (unsigned)f2bf(v0.x) | ((unsigned)f2bf(v0.y) << 16);
        u.y = (unsigned)f2bf(v0.z) | ((unsigned)f2bf(v0.w) << 16);
        u.z = (unsigned)f2bf(v1.x) | ((unsigned)f2bf(v1.y) << 16);
        u.w = (unsigned)f2bf(v1.z) | ((unsigned)f2bf(v1.w) << 16);
        ((uint4*)X)[(size_t)n * 16 + g] = u;
    }
}

// ---------------- weight prep: transpose + bf16 ----------------
__global__ void k_prepw(const float* __restrict__ Wt, const float* __restrict__ Wc,
                        unsigned short* __restrict__ WtT, unsigned short* __restrict__ WcT) {
    int tid = blockIdx.x * blockDim.x + threadIdx.x;
    const int T1 = 3 * 128 * 128;
    const int T2 = 3 * 256 * 128;
    if (tid < T1) {
        int l = tid >> 14, rem = tid & 16383;
        int n = rem >> 7, k = rem & 127;
        WtT[tid] = f2bf(Wt[l * 16384 + k * 128 + n]);
    } else if (tid < T1 + T2) {
        int t2 = tid - T1;
        int l = t2 >> 15, rem = t2 & 32767;
        int n = rem >> 8, k = rem & 255;
        WcT[t2] = f2bf(Wc[l * 32768 + k * 128 + n]);
    }
}

// ---------------- bf16 MFMA GEMM (bf16 inputs) ----------------
#define GM_ROWS 128
#define LDSP 136

__global__ __launch_bounds__(256) void k_gemm(
    const unsigned short* __restrict__ X1, const float* __restrict__ AB1, int relu1,
    const unsigned short* __restrict__ X2, const float* __restrict__ AB2, int relu2,
    const unsigned short* __restrict__ Wn, int Kpitch, int nstage,
    const float* __restrict__ bias, void* __restrict__ Y, int relu_out, int out_bf16,
    int N) {
    __shared__ unsigned short Ws[128 * LDSP];
    __shared__ unsigned short Xs[128 * LDSP];
    int t = threadIdx.x;
    int rowBase = blockIdx.x * GM_ROWS;
    int lane = t & 63, wave = t >> 6;
    int quad = lane >> 4, l16 = lane & 15;

    floatx4 acc[2][8];
#pragma unroll
    for (int i = 0; i < 2; ++i)
#pragma unroll
        for (int j = 0; j < 8; ++j) acc[i][j] = (floatx4){0.f, 0.f, 0.f, 0.f};

    int kg = (t & 15) * 8;
    int r0 = t >> 4;

    for (int s = 0; s < nstage; ++s) {
        const unsigned short* Xp = s ? X2 : X1;
        const float* ABp = s ? AB2 : AB1;
        int rl = s ? relu2 : relu1;
        int koff = s * 128;

#pragma unroll
        for (int j = 0; j < 8; ++j) {
            int n = r0 + 16 * j;
            *(short8*)&Ws[n * LDSP + kg] =
                *(const short8*)&Wn[(size_t)n * Kpitch + koff + kg];
        }
        floatx4 Av0 = {1.f, 1.f, 1.f, 1.f}, Av1 = Av0;
        floatx4 Bv0 = {0.f, 0.f, 0.f, 0.f}, Bv1 = Bv0;
        if (ABp) {
            Av0 = *(const floatx4*)&ABp[kg];
            Av1 = *(const floatx4*)&ABp[kg + 4];
            Bv0 = *(const floatx4*)&ABp[HID + kg];
            Bv1 = *(const floatx4*)&ABp[HID + kg + 4];
        }
#pragma unroll
        for (int j = 0; j < 8; ++j) {
            int r = r0 + 16 * j;
            int grow = rowBase + r;
            short8 raw = (short8){0, 0, 0, 0, 0, 0, 0, 0};
            if (grow < N) raw = *(const short8*)&Xp[(size_t)grow * HID + kg];
            if (ABp) {
                float x[8];
#pragma unroll
                for (int c = 0; c < 8; ++c)
                    x[c] = __uint_as_float(((unsigned)(unsigned short)raw[c]) << 16);
#pragma unroll
                for (int c = 0; c < 4; ++c) {
                    x[c] = fmaf(x[c], Av0[c], Bv0[c]);
                    x[4 + c] = fmaf(x[4 + c], Av1[c], Bv1[c]);
                }
                if (rl) {
#pragma unroll
                    for (int c = 0; c < 8; ++c) x[c] = fmaxf(x[c], 0.f);
                }
#pragma unroll
                for (int c = 0; c < 8; ++c) raw[c] = (short)f2bf(x[c]);
            }
            *(short8*)&Xs[r * LDSP + kg] = raw;
        }
        __syncthreads();

#pragma unroll
        for (int ks = 0; ks < 4; ++ks) {
            int kb = ks * 32 + quad * 8;
            short8 a0 = *(const short8*)&Xs[(wave * 32 + l16) * LDSP + kb];
            short8 a1 = *(const short8*)&Xs[(wave * 32 + 16 + l16) * LDSP + kb];
#pragma unroll
            for (int ni = 0; ni < 8; ++ni) {
                short8 b = *(const short8*)&Ws[(ni * 16 + l16) * LDSP + kb];
                acc[0][ni] = __builtin_amdgcn_mfma_f32_16x16x32_bf16(a0, b, acc[0][ni], 0, 0, 0);
                acc[1][ni] = __builtin_amdgcn_mfma_f32_16x16x32_bf16(a1, b, acc[1][ni], 0, 0, 0);
            }
        }
        __syncthreads();
    }

#pragma unroll
    for (int mi = 0; mi < 2; ++mi) {
#pragma unroll
        for (int ni = 0; ni < 8; ++ni) {
            int gcol = ni * 16 + l16;
            float bv = bias[gcol];
#pragma unroll
            for (int reg = 0; reg < 4; ++reg) {
                int grow = rowBase + wave * 32 + mi * 16 + quad * 4 + reg;
                if (grow < N) {
                    float v = acc[mi][ni][reg] + bv;
                    if (relu_out) v = fmaxf(v, 0.f);
                    if (out_bf16)
                        ((unsigned short*)Y)[(size_t)grow * HID + gcol] = f2bf(v);
                    else
                        ((float*)Y)[(size_t)grow * HID + gcol] = v;
                }
            }
        }
    }
}

// ---------------- aggregation + fused GraphNorm stats ----------------
// grid (ceil(N/64), 2); pass p=blockIdx.y covers features [64p, 64p+64).
// Each wave: 2 rows at a time (half-wave per row, 32 lanes x 2 feats = 64 feats),
// AGG_P pairs sequentially. Stats (sum, sumsq per feature) accumulated in
// registers -> shfl_xor(32) -> LDS -> striped global atomics.
#define AGG_P 8  // row-pairs per wave -> 64 rows per block

__global__ __launch_bounds__(256) void k_agg(
    const unsigned short* __restrict__ H, const int2* __restrict__ es,
    const unsigned* __restrict__ endp, const unsigned* __restrict__ cnt,
    unsigned short* __restrict__ M, float* __restrict__ Spart, int N) {
    __shared__ float Sb[128];  // [0..63] sum, [64..127] sumsq (64 local feats)
    int t = threadIdx.x;
    if (t < 128) Sb[t] = 0.f;
    __syncthreads();
    int wv = t >> 6, lane = t & 63;
    int half = lane >> 5, l = lane & 31;
    int p = blockIdx.y;
    int rowBase = blockIdx.x * (4 * AGG_P * 2) + wv * (AGG_P * 2);
    int hoff = p * 64 + l * 2;
    float s10 = 0.f, s11 = 0.f, s20 = 0.f, s21 = 0.f;

    for (int j = 0; j < AGG_P; ++j) {
        int myrow = rowBase + j * 2 + half;
        bool rv = myrow < N;
        unsigned e = 0, c = 0;
        if (rv) { e = endp[myrow]; c = cnt[myrow]; }
        unsigned ptr = e - c;
        unsigned cmax = max(c, (unsigned)__shfl_xor((int)c, 32));
        float a0 = 0.f, a1 = 0.f;
        for (unsigned k = 0; k < cmax; k += 2) {
            bool v0 = k < c, v1 = k + 1 < c;
            int2 e0 = es[v0 ? ptr : 0];
            int2 e1 = es[v1 ? ptr + 1 : 0];
            float w0 = v0 ? __int_as_float(e0.y) : 0.f;
            float w1 = v1 ? __int_as_float(e1.y) : 0.f;
            unsigned h0 = *(const unsigned*)&H[(size_t)e0.x * HID + hoff];
            unsigned h1 = *(const unsigned*)&H[(size_t)e1.x * HID + hoff];
            a0 = fmaf(w0, bflo(h0), a0);
            a1 = fmaf(w0, bfhi(h0), a1);
            a0 = fmaf(w1, bflo(h1), a0);
            a1 = fmaf(w1, bfhi(h1), a1);
            ptr += 2;
        }
        if (rv) {
            s10 += a0; s11 += a1;
            s20 += a0 * a0; s21 += a1 * a1;
            unsigned m01 = (unsigned)f2bf(a0) | ((unsigned)f2bf(a1) << 16);
            *(unsigned*)&M[(size_t)myrow * HID + hoff] = m01;
        }
    }
    // combine the two half-waves (same features, different rows)
    s10 += __shfl_xor(s10, 32);
    s11 += __shfl_xor(s11, 32);
    s20 += __shfl_xor(s20, 32);
    s21 += __shfl_xor(s21, 32);
    if (half == 0) {
        atomicAdd(&Sb[l * 2], s10);
        atomicAdd(&Sb[l * 2 + 1], s11);
        atomicAdd(&Sb[64 + l * 2], s20);
        atomicAdd(&Sb[64 + l * 2 + 1], s21);
    }
    __syncthreads();
    if (t < 128) {
        int f_loc = t & 63;
        int target = (t < 64) ? (p * 64 + f_loc) : (128 + p * 64 + f_loc);
        atomicAdd(&Spart[(blockIdx.x & 7) * 256 + target], Sb[t]);
    }
}

// ---------------- column-wise stats for y (bf16 input, striped output) ----------------
__global__ __launch_bounds__(256) void k_reduce(const unsigned short* __restrict__ Y,
                                                float* __restrict__ S, int N) {
    __shared__ float sh[4][256];
    int t = threadIdx.x;
    int fg = t & 63, sub = t >> 6;
    float s1a = 0.f, s1b = 0.f, s2a = 0.f, s2b = 0.f;
    for (int r = blockIdx.x * 4 + sub; r < N; r += gridDim.x * 4) {
        unsigned v = *(const unsigned*)&Y[(size_t)r * HID + fg * 2];
        float va = bflo(v), vb = bfhi(v);
        s1a += va; s1b += vb;
        s2a += va * va; s2b += vb * vb;
    }
    sh[sub][fg] = s1a;
    sh[sub][64 + fg] = s1b;
    sh[sub][128 + fg] = s2a;
    sh[sub][192 + fg] = s2b;
    __syncthreads();
    {
        float v = sh[0][t] + sh[1][t] + sh[2][t] + sh[3][t];
        int region = t >> 6, f_loc = t & 63;
        int base = (region >= 2) ? 128 : 0;
        int f = 2 * f_loc + (region & 1);
        atomicAdd(&S[(blockIdx.x & 7) * 256 + base + f], v);
    }
}

// A = gamma*rsqrt(var+eps); B = beta - A*alpha*mu  (sums over 8 striped copies)
__global__ void k_finalize(const float* __restrict__ S, const float* __restrict__ gamma,
                           const float* __restrict__ beta, const float* __restrict__ alpha,
                           float* __restrict__ AB, float invN) {
    int f = threadIdx.x;
    float sum = 0.f, sq = 0.f;
#pragma unroll
    for (int c = 0; c < 8; ++c) {
        sum += S[c * 256 + f];
        sq += S[c * 256 + 128 + f];
    }
    float mu = sum * invN;
    float ex2 = sq * invN;
    float a = alpha[f];
    float var = ex2 - 2.f * a * mu * mu + a * a * mu * mu;
    float rs = rsqrtf(var + 1e-5f);
    float A = gamma[f] * rs;
    float B = beta[f] - A * a * mu;
    AB[f] = A;
    AB[HID + f] = B;
}

// ---------------------------------------------------------------------------
extern "C" void kernel_launch(void* const* d_in, const int* in_sizes, int n_in,
                              void* d_out, int out_size, void* d_ws, size_t ws_size,
                              hipStream_t stream) {
    const int*   x_idx = (const int*)d_in[0];
    const int*   ei    = (const int*)d_in[1];
    const float* ew    = (const float*)d_in[2];
    const float* emb   = (const float*)d_in[3];
    const float* Wt    = (const float*)d_in[4];
    const float* bt    = (const float*)d_in[5];
    const float* Wc    = (const float*)d_in[6];
    const float* bc    = (const float*)d_in[7];
    const float* cg_g  = (const float*)d_in[8];
    const float* cg_b  = (const float*)d_in[9];
    const float* cg_a  = (const float*)d_in[10];
    const float* gn_g  = (const float*)d_in[11];
    const float* gn_b  = (const float*)d_in[12];
    const float* gn_a  = (const float*)d_in[13];
    const int N = in_sizes[0];
    const int E = in_sizes[2];
    const int* row = ei;
    const int* col = ei + E;

    char* ws = (char*)d_ws;
    size_t off = 0;
    auto alloc = [&](size_t bytes) -> void* {
        size_t o = (off + 511) & ~(size_t)511;
        off = o + bytes;
        return (void*)(ws + o);
    };
    unsigned* cursor = (unsigned*)alloc(NB * 4);                // zeroed
    float*    Spart  = (float*)alloc(5 * 8 * 256 * 4);          // zeroed (stats, striped x8)
    size_t zero_end = off;
    unsigned* outbase = (unsigned*)alloc(NB * 4);
    unsigned* endp    = (unsigned*)alloc((size_t)N * 4);
    unsigned* cnt     = (unsigned*)alloc((size_t)N * 4);
    float*    AB      = (float*)alloc(5 * 256 * 4);
    unsigned short* WtT = (unsigned short*)alloc((size_t)3 * 128 * 128 * 2);
    unsigned short* WcT = (unsigned short*)alloc((size_t)3 * 128 * 256 * 2);
    int2*     binned  = (int2*)alloc((size_t)NB * CAPB * 8);    // 33.6 MB
    int2*     edge_s  = (int2*)alloc((size_t)E * 8);            // 25.6 MB
    unsigned short* H  = (unsigned short*)alloc((size_t)N * HID * 2);
    unsigned short* Xe = (unsigned short*)alloc((size_t)N * HID * 2);
    unsigned short* M  = (unsigned short*)alloc((size_t)N * HID * 2);
    if (off > ws_size) {
        fprintf(stderr, "kernel_launch: ws too small (%zu > %zu)\n", off, ws_size);
        return;
    }

    hipMemsetAsync(d_ws, 0, zero_end, stream);

    k_prepw<<<(3 * 128 * 128 + 3 * 256 * 128 + 255) / 256, 256, 0, stream>>>(Wt, Wc, WtT, WcT);
    k_binA<<<(E + TILE_A - 1) / TILE_A, 256, 0, stream>>>(row, col, ew, binned, cursor, E);
    k_bscan<<<1, 256, 0, stream>>>(cursor, outbase);
    k_binB<<<NB, 256, 0, stream>>>(binned, cursor, outbase, edge_s, endp, cnt, N);
    k_gather<<<(N * 16 + 255) / 256, 256, 0, stream>>>(x_idx, emb, Xe, N);

    int gemm_blocks = (N + GM_ROWS - 1) / GM_ROWS;
    auto gemm = [&](const unsigned short* X1, const float* AB1, int rl1,
                    const unsigned short* X2, const float* AB2, int rl2,
                    const unsigned short* Wn, int Kpitch, int nstage,
                    const float* bias, void* Y, int relu_out, int out_bf16) {
        k_gemm<<<gemm_blocks, 256, 0, stream>>>(X1, AB1, rl1, X2, AB2, rl2, Wn, Kpitch,
                                                nstage, bias, Y, relu_out, out_bf16, N);
    };
    dim3 aggG((N + 63) / 64, 2);
    auto agg = [&](int stage) {
        k_agg<<<aggG, 256, 0, stream>>>(H, edge_s, endp, cnt, M, Spart + stage * 2048, N);
    };
    auto fin = [&](int stage, const float* g, const float* b, const float* a) {
        k_finalize<<<1, 128, 0, stream>>>(Spart + stage * 2048, g, b, a, AB + stage * 256,
                                          1.0f / (float)N);
    };
    auto red = [&](const unsigned short* buf, int stage) {
        k_reduce<<<256, 256, 0, stream>>>(buf, Spart + stage * 2048, N);
    };

    // ---- Layer 0 ----
    gemm(Xe, nullptr, 0, nullptr, nullptr, 0, WtT, 128, 1, bt, H, 1, 1);
    agg(0);
    fin(0, cg_g, cg_b, cg_a);
    gemm(M, AB + 0 * 256, 0, Xe, nullptr, 0, WcT, 256, 2, bc, Xe, 0, 1);  // y0 -> Xe (in-place)
    red(Xe, 1);
    fin(1, gn_g, gn_b, gn_a);

    // ---- Layer 1 ----  (x1 = relu(gn0(y0)) applied on load via AB1)
    gemm(Xe, AB + 1 * 256, 1, nullptr, nullptr, 0, WtT + 16384, 128, 1, bt + 128, H, 1, 1);
    agg(2);
    fin(2, cg_g + 128, cg_b + 128, cg_a + 128);
    gemm(M, AB + 2 * 256, 0, Xe, AB + 1 * 256, 1, WcT + 32768, 256, 2, bc + 128, Xe, 0, 1);
    red(Xe, 3);
    fin(3, gn_g + 128, gn_b + 128, gn_a + 128);

    // ---- Layer 2 ----  (x2 = relu(gn1(y1)) applied on load via AB3)
    gemm(Xe, AB + 3 * 256, 1, nullptr, nullptr, 0, WtT + 2 * 16384, 128, 1, bt + 256, H, 1, 1);
    agg(4);
    fin(4, cg_g + 256, cg_b + 256, cg_a + 256);
    gemm(M, AB + 4 * 256, 0, Xe, AB + 3 * 256, 1, WcT + 2 * 32768, 256, 2, bc + 256,
         d_out, 0, 0);
}